// Round 3
// baseline (137.948 us; speedup 1.0000x reference)
//
#include <hip/hip_runtime.h>

typedef short bf16x8 __attribute__((ext_vector_type(8)));
typedef float f32x4 __attribute__((ext_vector_type(4)));
typedef unsigned short u16;
typedef u16 u16x8 __attribute__((ext_vector_type(8)));
typedef u16 u16x4 __attribute__((ext_vector_type(4)));

#define L_ 2048
#define D_ 512
#define H_ 8
#define DH_ 64
#define DIN 508

static __device__ __forceinline__ u16 f2b(float f){
  unsigned u = __builtin_bit_cast(unsigned, f);
  unsigned r = u + 0x7fffu + ((u >> 16) & 1u);   // round-to-nearest-even
  return (u16)(r >> 16);
}
static __device__ __forceinline__ float b2f(u16 u){
  unsigned x = ((unsigned)u) << 16;
  return __builtin_bit_cast(float, x);
}
static __device__ __forceinline__ bf16x8 asbf(u16x8 v){
  return __builtin_bit_cast(bf16x8, v);
}
#define MFMA16(a,b,c) __builtin_amdgcn_mfma_f32_16x16x32_bf16(a,b,c,0,0,0)

// ---------------------------------------------------------------------------
// Kernel 1: fused QKV projection.  C[i][n] = sum_k Xpad[i][k] * W[n][k]
// Q,K stored bf16 as [bh][l][dh]; V stored TRANSPOSED bf16 as [bh][dh][l].
// ---------------------------------------------------------------------------
__global__ __launch_bounds__(512) void proj_kernel(
    const float* __restrict__ inp, const float* __restrict__ Wq,
    const float* __restrict__ Wk, const float* __restrict__ Wv,
    u16* __restrict__ Qg, u16* __restrict__ Kg, u16* __restrict__ Vt)
{
  __shared__ u16 Xl[128*72];   // stride 72 u16 = 36dw (== 4 mod 32): conflict-free
  __shared__ u16 Wl[128*72];
  const int t = threadIdx.x;
  const int lane = t & 63, wid = t >> 6;
  const int wr = wid >> 2, wc = wid & 3;          // 2x4 wave grid -> 64x32 per wave
  const int i0 = blockIdx.x * 128;
  const int j0 = blockIdx.y * 128;
  const int mat = j0 >> 9;                        // 0:Q 1:K 2:V
  const float* __restrict__ W = (mat==0) ? Wq : (mat==1) ? Wk : Wv;
  const int jbase = j0 & 511;
  const int srow = t >> 3, sc8 = (t & 7) * 8;

  f32x4 acc[4][2];
  #pragma unroll
  for (int a=0;a<4;++a){
    #pragma unroll
    for (int bq=0;bq<2;++bq){ f32x4 z = {0.f,0.f,0.f,0.f}; acc[a][bq] = z; }
  }

  for (int kt=0; kt<8; ++kt){
    const int k0 = kt*64;
    __syncthreads();
    #pragma unroll
    for (int it=0; it<2; ++it){
      const int r = srow + 64*it;
      u16x8 xb;
      const int gi = i0 + r;
      #pragma unroll
      for (int e=0;e<8;++e){
        const int k = k0 + sc8 + e;
        float v = (k>=2 && k<510) ? inp[gi*DIN + (k-2)] : 0.f;
        xb[e] = f2b(v);
      }
      *(u16x8*)&Xl[r*72 + sc8] = xb;
      const float* wp = W + (jbase + r)*D_ + k0 + sc8;
      u16x8 wb;
      #pragma unroll
      for (int e=0;e<8;++e) wb[e] = f2b(wp[e]);
      *(u16x8*)&Wl[r*72 + sc8] = wb;
    }
    __syncthreads();
    #pragma unroll
    for (int ks=0; ks<2; ++ks){
      const int ko = ks*32 + (lane>>4)*8;
      bf16x8 af[4], bfr[2];
      #pragma unroll
      for (int fm=0; fm<4; ++fm)
        af[fm] = *(const bf16x8*)&Xl[(wr*64 + fm*16 + (lane&15))*72 + ko];
      #pragma unroll
      for (int fn=0; fn<2; ++fn)
        bfr[fn] = *(const bf16x8*)&Wl[(wc*32 + fn*16 + (lane&15))*72 + ko];
      #pragma unroll
      for (int fm=0; fm<4; ++fm){
        #pragma unroll
        for (int fn=0; fn<2; ++fn)
          acc[fm][fn] = MFMA16(af[fm], bfr[fn], acc[fm][fn]);
      }
    }
  }
  #pragma unroll
  for (int fm=0; fm<4; ++fm){
    const int ibase = i0 + wr*64 + fm*16 + (lane>>4)*4;
    const int b = ibase >> 11;
    const int li = ibase & (L_-1);
    #pragma unroll
    for (int fn=0; fn<2; ++fn){
      const int n = j0 + wc*32 + fn*16 + (lane&15);
      const int h = (n>>6) & 7;
      const int dh = n & 63;
      if (mat == 2){
        u16x4 pk;
        #pragma unroll
        for (int r=0;r<4;++r) pk[r] = f2b(acc[fm][fn][r]);
        *(u16x4*)&Vt[((size_t)(b*H_+h)*DH_ + dh)*L_ + li] = pk;   // contiguous in l
      } else {
        u16* dst = ((mat==0)? Qg : Kg) + ((size_t)(b*H_+h)*L_ + li)*DH_ + dh;
        #pragma unroll
        for (int r=0;r<4;++r) dst[(size_t)r*DH_] = f2b(acc[fm][fn][r]);
      }
    }
  }
}

// ---------------------------------------------------------------------------
// Kernel 2: attention, two-pass over K (recompute QK^T).
// Block = 32 q-rows of one (b,h), 512 thr = 8 waves.
// K fragments are read DIRECTLY from global (L2-resident, 256 KB/bh): pass A
// has ZERO barriers; pass B has ONE barrier/tile via double-buffered Vl/Pt.
// attn stores are nontemporal so the 268 MB stream doesn't evict K/V from L2.
// S^T form: mfma(K-frag, Q-frag) -> lane holds (m=(lane>>4)*4+r, q=lane&15).
// ---------------------------------------------------------------------------
__global__ __launch_bounds__(512, 4) void attn_kernel(
    const u16* __restrict__ Qg, const u16* __restrict__ Kg,
    const u16* __restrict__ Vt, float* __restrict__ attn, float* __restrict__ Og)
{
  __shared__ u16 Vbuf[2*64*136];   // 34816 B (double-buffered V tiles)
  __shared__ u16 Pbuf[2*32*136];   // 17408 B (double-buffered P tiles)
  __shared__ float inv_rs[32];
  float* rsp = (float*)Vbuf;       // aliased: used only between pass A and B

  const int t = threadIdx.x, lane = t & 63, wid = t >> 6;
  const int q0 = blockIdx.x * 32;
  const int bh = blockIdx.y;
  const u16* Qp = Qg + ((size_t)bh*L_ + q0)*DH_;
  const u16* Kp = Kg + (size_t)bh*L_*DH_;
  const u16* Vp = Vt + (size_t)bh*DH_*L_;

  // Q fragments: rows q = qi*16 + (lane&15), cols k = ks*32 + (lane>>4)*8
  bf16x8 qf[2][2];
  #pragma unroll
  for (int qi=0;qi<2;++qi){
    #pragma unroll
    for (int ks=0;ks<2;++ks)
      qf[qi][ks] = *(const bf16x8*)&Qp[(size_t)(qi*16 + (lane&15))*DH_ + ks*32 + (lane>>4)*8];
  }

  const int vr0 = t>>4, vcm = (t&15)*8;    // V staging: rows vr0, vr0+32
  const int g4 = (lane>>4)*8;
  const int mrow = wid*16 + (lane&15);     // this wave's K rows (m slice)

  // ---------------- pass A: row sums of exp(S), no LDS, no barriers --------
  float racc0 = 0.f, racc1 = 0.f;
  {
    u16x8 nk0 = *(const u16x8*)&Kp[(size_t)mrow*DH_ + g4];
    u16x8 nk1 = *(const u16x8*)&Kp[(size_t)mrow*DH_ + 32 + g4];
    for (int kt=0; kt<16; ++kt){
      bf16x8 kf0 = asbf(nk0), kf1 = asbf(nk1);
      if (kt < 15){
        nk0 = *(const u16x8*)&Kp[(size_t)((kt+1)*128 + mrow)*DH_ + g4];
        nk1 = *(const u16x8*)&Kp[(size_t)((kt+1)*128 + mrow)*DH_ + 32 + g4];
      }
      f32x4 s0 = {0.f,0.f,0.f,0.f}, s1 = {0.f,0.f,0.f,0.f};
      s0 = MFMA16(kf0, qf[0][0], s0); s0 = MFMA16(kf1, qf[0][1], s0);
      s1 = MFMA16(kf0, qf[1][0], s1); s1 = MFMA16(kf1, qf[1][1], s1);
      #pragma unroll
      for (int r=0;r<4;++r){
        racc0 += __expf(s0[r]*0.125f);
        racc1 += __expf(s1[r]*0.125f);
      }
    }
  }
  racc0 += __shfl_xor(racc0, 16); racc0 += __shfl_xor(racc0, 32);
  racc1 += __shfl_xor(racc1, 16); racc1 += __shfl_xor(racc1, 32);
  if (lane < 16){ rsp[wid*32 + lane] = racc0; rsp[wid*32 + 16 + lane] = racc1; }
  __syncthreads();
  if (t < 32){
    float s = 0.f;
    #pragma unroll
    for (int w=0;w<8;++w) s += rsp[w*32 + t];
    inv_rs[t] = 1.f/s;
  }
  __syncthreads();                          // rsp (alias of Vbuf) dead after this
  const float invq0 = inv_rs[lane&15];
  const float invq1 = inv_rs[16 + (lane&15)];

  // ---------------- pass B: attn stores + PV, ONE barrier per tile ---------
  const int qpv = wid>>2, d0 = (wid&3)*16;  // PV: wave owns 16q x 16d frag
  f32x4 o0 = {0.f,0.f,0.f,0.f}, o1 = {0.f,0.f,0.f,0.f};
  float* arow0 = attn + ((size_t)bh*L_ + q0 + (lane&15))*L_ + wid*16 + (lane>>4)*4;
  float* arow1 = arow0 + (size_t)16*L_;

  u16x8 nk0 = *(const u16x8*)&Kp[(size_t)mrow*DH_ + g4];
  u16x8 nk1 = *(const u16x8*)&Kp[(size_t)mrow*DH_ + 32 + g4];
  u16x8 va = *(const u16x8*)&Vp[(size_t)vr0*L_ + vcm];
  u16x8 vb = *(const u16x8*)&Vp[(size_t)(32+vr0)*L_ + vcm];
  for (int kt=0; kt<16; ++kt){
    u16* Vc = Vbuf + (kt&1)*64*136;
    u16* Pc = Pbuf + (kt&1)*32*136;
    // stage V tile (prev PV on this buffer finished before last barrier)
    *(u16x8*)&Vc[vr0*136 + vcm] = va;
    *(u16x8*)&Vc[(32+vr0)*136 + vcm] = vb;
    // S^T from direct-global K fragments
    bf16x8 kf0 = asbf(nk0), kf1 = asbf(nk1);
    f32x4 s0 = {0.f,0.f,0.f,0.f}, s1 = {0.f,0.f,0.f,0.f};
    s0 = MFMA16(kf0, qf[0][0], s0); s0 = MFMA16(kf1, qf[0][1], s0);
    s1 = MFMA16(kf0, qf[1][0], s1); s1 = MFMA16(kf1, qf[1][1], s1);
    // prefetch next K/V
    if (kt < 15){
      nk0 = *(const u16x8*)&Kp[(size_t)((kt+1)*128 + mrow)*DH_ + g4];
      nk1 = *(const u16x8*)&Kp[(size_t)((kt+1)*128 + mrow)*DH_ + 32 + g4];
      va = *(const u16x8*)&Vp[(size_t)vr0*L_ + (kt+1)*128 + vcm];
      vb = *(const u16x8*)&Vp[(size_t)(32+vr0)*L_ + (kt+1)*128 + vcm];
    }
    // exp -> normalized attn (nontemporal) + bf16 P tile
    f32x4 a0, a1; u16x4 p0, p1;
    float e;
    e = __expf(s0[0]*0.125f); a0[0] = e*invq0; p0[0] = f2b(e);
    e = __expf(s0[1]*0.125f); a0[1] = e*invq0; p0[1] = f2b(e);
    e = __expf(s0[2]*0.125f); a0[2] = e*invq0; p0[2] = f2b(e);
    e = __expf(s0[3]*0.125f); a0[3] = e*invq0; p0[3] = f2b(e);
    e = __expf(s1[0]*0.125f); a1[0] = e*invq1; p1[0] = f2b(e);
    e = __expf(s1[1]*0.125f); a1[1] = e*invq1; p1[1] = f2b(e);
    e = __expf(s1[2]*0.125f); a1[2] = e*invq1; p1[2] = f2b(e);
    e = __expf(s1[3]*0.125f); a1[3] = e*invq1; p1[3] = f2b(e);
    __builtin_nontemporal_store(a0, (f32x4*)&arow0[kt*128]);
    __builtin_nontemporal_store(a1, (f32x4*)&arow1[kt*128]);
    *(u16x4*)&Pc[(lane&15)*136 + wid*16 + (lane>>4)*4] = p0;
    *(u16x4*)&Pc[(16 + (lane&15))*136 + wid*16 + (lane>>4)*4] = p1;
    __syncthreads();                         // Vc/Pc ready for all waves
    #pragma unroll
    for (int ms=0; ms<4; ++ms){
      bf16x8 pa = *(const bf16x8*)&Pc[(qpv*16 + (lane&15))*136 + ms*32 + g4];
      bf16x8 vv = *(const bf16x8*)&Vc[(d0 + (lane&15))*136 + ms*32 + g4];
      if (ms&1) o1 = MFMA16(pa, vv, o1); else o0 = MFMA16(pa, vv, o0);
    }
  }
  {
    const int b = bh>>3, h = bh&7;
    #pragma unroll
    for (int r=0;r<4;++r){
      const int qr = qpv*16 + (lane>>4)*4 + r;
      Og[((size_t)(b*L_ + q0 + qr))*D_ + h*DH_ + d0 + (lane&15)] = (o0[r]+o1[r])*inv_rs[qr];
    }
  }
}

// ---------------------------------------------------------------------------
// Kernel 3: residual add + LayerNorm over d=512 + slice to 508 cols.
// ---------------------------------------------------------------------------
__global__ __launch_bounds__(256) void ln_kernel(
    const float* __restrict__ Og, const float* __restrict__ inp,
    const float* __restrict__ gamma, const float* __restrict__ beta,
    float* __restrict__ out0)
{
  const int row = blockIdx.x, t = threadIdx.x;
  const int lane = t & 63, wid = t >> 6;
  const int c2 = t + 256;
  const float x1 = (t >= 2) ? inp[(size_t)row*DIN + t-2] : 0.f;
  const float x2 = (c2 < 510) ? inp[(size_t)row*DIN + c2-2] : 0.f;
  const float y1 = Og[(size_t)row*D_ + t]  + x1;
  const float y2 = Og[(size_t)row*D_ + c2] + x2;
  float s = y1 + y2, ss = y1*y1 + y2*y2;
  #pragma unroll
  for (int off=1; off<64; off<<=1){
    s  += __shfl_xor(s,  off);
    ss += __shfl_xor(ss, off);
  }
  __shared__ float red[4][2];
  if (lane == 0){ red[wid][0] = s; red[wid][1] = ss; }
  __syncthreads();
  s  = red[0][0]+red[1][0]+red[2][0]+red[3][0];
  ss = red[0][1]+red[1][1]+red[2][1]+red[3][1];
  const float mu   = s * (1.f/512.f);
  const float var  = ss * (1.f/512.f) - mu*mu;
  const float rstd = rsqrtf(var + 1e-6f);
  const float z1 = (y1 - mu)*rstd*gamma[t]  + beta[t];
  const float z2 = (y2 - mu)*rstd*gamma[c2] + beta[c2];
  if (t >= 2)   out0[(size_t)row*DIN + t-2]  = z1;
  if (c2 < 510) out0[(size_t)row*DIN + c2-2] = z2;
}

// ---------------------------------------------------------------------------
extern "C" void kernel_launch(void* const* d_in, const int* in_sizes, int n_in,
                              void* d_out, int out_size, void* d_ws, size_t ws_size,
                              hipStream_t stream) {
  const float* inp   = (const float*)d_in[0];
  const float* Wq    = (const float*)d_in[1];
  const float* Wk    = (const float*)d_in[2];
  const float* Wv    = (const float*)d_in[3];
  const float* gamma = (const float*)d_in[4];
  const float* beta  = (const float*)d_in[5];

  char* ws = (char*)d_ws;
  u16*   Qg = (u16*)(ws);                        // 4 MB
  u16*   Kg = (u16*)(ws + 4194304);              // 4 MB
  u16*   Vt = (u16*)(ws + 8388608);              // 4 MB, transposed [bh][dh][l]
  float* Og = (float*)(ws + 12582912);           // 8 MB

  float* out0 = (float*)d_out;                   // (2,2048,508)
  float* attn = out0 + 2080768;                  // (2,8,2048,2048)

  proj_kernel<<<dim3(32,12), 512, 0, stream>>>(inp, Wq, Wk, Wv, Qg, Kg, Vt);
  attn_kernel<<<dim3(64,16), 512, 0, stream>>>(Qg, Kg, Vt, attn, Og);
  ln_kernel<<<4096, 256, 0, stream>>>(Og, inp, gamma, beta, out0);
}

// Round 4
// 126.082 us; speedup vs baseline: 1.0941x; 1.0941x over previous
//
#include <hip/hip_runtime.h>

typedef short bf16x8 __attribute__((ext_vector_type(8)));
typedef float f32x4 __attribute__((ext_vector_type(4)));
typedef unsigned short u16;
typedef u16 u16x8 __attribute__((ext_vector_type(8)));
typedef u16 u16x4 __attribute__((ext_vector_type(4)));

#define L_ 2048
#define D_ 512
#define H_ 8
#define DH_ 64
#define DIN 508

static __device__ __forceinline__ u16 f2b(float f){
  unsigned u = __builtin_bit_cast(unsigned, f);
  unsigned r = u + 0x7fffu + ((u >> 16) & 1u);   // round-to-nearest-even
  return (u16)(r >> 16);
}
static __device__ __forceinline__ float b2f(u16 u){
  unsigned x = ((unsigned)u) << 16;
  return __builtin_bit_cast(float, x);
}
static __device__ __forceinline__ bf16x8 asbf(u16x8 v){
  return __builtin_bit_cast(bf16x8, v);
}
#define MFMA16(a,b,c) __builtin_amdgcn_mfma_f32_16x16x32_bf16(a,b,c,0,0,0)

// ---------------------------------------------------------------------------
// Kernel 0: one-shot fp32 -> bf16 conversion (+ zero-pad X).
// Xb: [4096][512] bf16 (cols 0,1,510,511 = 0), Wb: [1536][512] bf16.
// ---------------------------------------------------------------------------
__global__ __launch_bounds__(512) void cvt_kernel(
    const float* __restrict__ inp, const float* __restrict__ Wq,
    const float* __restrict__ Wk, const float* __restrict__ Wv,
    u16* __restrict__ Xb, u16* __restrict__ Wb)
{
  const int tid = blockIdx.x*512 + threadIdx.x;
  if (tid < 262144) {                       // X part: 4096*512/8 threads
    const int idx8 = tid*8;
    const int row = idx8 >> 9, col = idx8 & 511;
    u16x8 o;
    #pragma unroll
    for (int e=0;e<8;++e){
      const int c = col+e;
      const float v = (c>=2 && c<510) ? inp[(size_t)row*DIN + (c-2)] : 0.f;
      o[e] = f2b(v);
    }
    *(u16x8*)&Xb[idx8] = o;
  } else {                                  // W part: 1536*512/8 threads
    const int idx8 = (tid - 262144)*8;
    const int row = idx8 >> 9, col = idx8 & 511;
    const float* __restrict__ W = (row < 512) ? Wq : (row < 1024) ? Wk : Wv;
    const float* p = &W[(size_t)(row & 511)*D_ + col];
    u16x8 o;
    #pragma unroll
    for (int e=0;e<8;++e) o[e] = f2b(p[e]);
    *(u16x8*)&Wb[idx8] = o;
  }
}

// ---------------------------------------------------------------------------
// Kernel 1: QKV projection, pure-bf16 GEMM.  C[i][n] = sum_k Xb[i][k]*Wb[n][k]
// Q,K stored bf16 as [bh][l][dh]; V stored TRANSPOSED bf16 as [bh][dh][l].
// ---------------------------------------------------------------------------
__global__ __launch_bounds__(512) void proj_kernel(
    const u16* __restrict__ Xb, const u16* __restrict__ Wb,
    u16* __restrict__ Qg, u16* __restrict__ Kg, u16* __restrict__ Vt)
{
  __shared__ u16 Xl[128*72];   // stride 72 u16 = 36dw (== 4 mod 32): conflict-free
  __shared__ u16 Wl[128*72];
  const int t = threadIdx.x;
  const int lane = t & 63, wid = t >> 6;
  const int wr = wid >> 2, wc = wid & 3;          // 2x4 wave grid -> 64x32 per wave
  const int i0 = blockIdx.x * 128;
  const int j0 = blockIdx.y * 128;                // 0..1535
  const int mat = j0 >> 9;                        // 0:Q 1:K 2:V
  const int srow = t >> 3, sc8 = (t & 7) * 8;

  f32x4 acc[4][2];
  #pragma unroll
  for (int a=0;a<4;++a){
    #pragma unroll
    for (int bq=0;bq<2;++bq){ f32x4 z = {0.f,0.f,0.f,0.f}; acc[a][bq] = z; }
  }

  // register prefetch of first tile
  u16x8 xa0 = *(const u16x8*)&Xb[(size_t)(i0+srow)*D_ + sc8];
  u16x8 xa1 = *(const u16x8*)&Xb[(size_t)(i0+64+srow)*D_ + sc8];
  u16x8 wa0 = *(const u16x8*)&Wb[(size_t)(j0+srow)*D_ + sc8];
  u16x8 wa1 = *(const u16x8*)&Wb[(size_t)(j0+64+srow)*D_ + sc8];

  for (int kt=0; kt<8; ++kt){
    __syncthreads();
    *(u16x8*)&Xl[srow*72 + sc8] = xa0;
    *(u16x8*)&Xl[(64+srow)*72 + sc8] = xa1;
    *(u16x8*)&Wl[srow*72 + sc8] = wa0;
    *(u16x8*)&Wl[(64+srow)*72 + sc8] = wa1;
    __syncthreads();
    if (kt < 7){
      const int k1 = (kt+1)*64;
      xa0 = *(const u16x8*)&Xb[(size_t)(i0+srow)*D_ + k1 + sc8];
      xa1 = *(const u16x8*)&Xb[(size_t)(i0+64+srow)*D_ + k1 + sc8];
      wa0 = *(const u16x8*)&Wb[(size_t)(j0+srow)*D_ + k1 + sc8];
      wa1 = *(const u16x8*)&Wb[(size_t)(j0+64+srow)*D_ + k1 + sc8];
    }
    #pragma unroll
    for (int ks=0; ks<2; ++ks){
      const int ko = ks*32 + (lane>>4)*8;
      bf16x8 af[4], bfr[2];
      #pragma unroll
      for (int fm=0; fm<4; ++fm)
        af[fm] = *(const bf16x8*)&Xl[(wr*64 + fm*16 + (lane&15))*72 + ko];
      #pragma unroll
      for (int fn=0; fn<2; ++fn)
        bfr[fn] = *(const bf16x8*)&Wl[(wc*32 + fn*16 + (lane&15))*72 + ko];
      #pragma unroll
      for (int fm=0; fm<4; ++fm){
        #pragma unroll
        for (int fn=0; fn<2; ++fn)
          acc[fm][fn] = MFMA16(af[fm], bfr[fn], acc[fm][fn]);
      }
    }
  }
  #pragma unroll
  for (int fm=0; fm<4; ++fm){
    const int ibase = i0 + wr*64 + fm*16 + (lane>>4)*4;
    const int b = ibase >> 11;
    const int li = ibase & (L_-1);
    #pragma unroll
    for (int fn=0; fn<2; ++fn){
      const int n = j0 + wc*32 + fn*16 + (lane&15);
      const int h = (n>>6) & 7;
      const int dh = n & 63;
      if (mat == 2){
        u16x4 pk;
        #pragma unroll
        for (int r=0;r<4;++r) pk[r] = f2b(acc[fm][fn][r]);
        *(u16x4*)&Vt[((size_t)(b*H_+h)*DH_ + dh)*L_ + li] = pk;   // contiguous in l
      } else {
        u16* dst = ((mat==0)? Qg : Kg) + ((size_t)(b*H_+h)*L_ + li)*DH_ + dh;
        #pragma unroll
        for (int r=0;r<4;++r) dst[(size_t)r*DH_] = f2b(acc[fm][fn][r]);
      }
    }
  }
}

// ---------------------------------------------------------------------------
// Kernel 2: attention, two-pass over K (recompute QK^T).
// Block = 32 q-rows of one (b,h), 512 thr = 8 waves.
// Round-2 skeleton (LDS-staged K/V, 2 barriers pass A, 3 barriers pass B) +
// NEW: attn stores are COALESCED (via the Pt LDS tile, 512 B per 16-lane
// group) and nontemporal (safe now; protects L2 K/V residency).
// S^T form: mfma(K-frag, Q-frag) -> lane holds (m=(lane>>4)*4+r, q=lane&15).
// ---------------------------------------------------------------------------
__global__ __launch_bounds__(512, 4) void attn_kernel(
    const u16* __restrict__ Qg, const u16* __restrict__ Kg,
    const u16* __restrict__ Vt, float* __restrict__ attn, float* __restrict__ Og)
{
  __shared__ u16 Kl[128*72];     // 18432 B
  __shared__ u16 Vl[64*136];     // 17408 B
  __shared__ u16 Pt[32*136];     //  8704 B
  __shared__ float rsp[8][32];
  __shared__ float inv_rs[32];

  const int t = threadIdx.x, lane = t & 63, wid = t >> 6;
  const int q0 = blockIdx.x * 32;
  const int bh = blockIdx.y;
  const u16* Qp = Qg + ((size_t)bh*L_ + q0)*DH_;
  const u16* Kp = Kg + (size_t)bh*L_*DH_;
  const u16* Vp = Vt + (size_t)bh*DH_*L_;

  // Q fragments: rows q = qi*16 + (lane&15), cols k = ks*32 + (lane>>4)*8
  bf16x8 qf[2][2];
  #pragma unroll
  for (int qi=0;qi<2;++qi){
    #pragma unroll
    for (int ks=0;ks<2;++ks)
      qf[qi][ks] = *(const bf16x8*)&Qp[(size_t)(qi*16 + (lane&15))*DH_ + ks*32 + (lane>>4)*8];
  }

  const int kr0 = t>>3, kc8 = (t&7)*8;     // K staging: rows kr0, kr0+64
  const int vr0 = t>>4, vcm = (t&15)*8;    // V staging: rows vr0, vr0+32
  const int g4 = (lane>>4)*8;
  const int mrow = wid*16 + (lane&15);     // this wave's K rows (m slice)

  // ---------------- pass A: row sums of exp(S) ----------------
  float racc0 = 0.f, racc1 = 0.f;
  u16x8 ka = *(const u16x8*)&Kp[(size_t)kr0*DH_ + kc8];
  u16x8 kb = *(const u16x8*)&Kp[(size_t)(64+kr0)*DH_ + kc8];
  for (int kt=0; kt<16; ++kt){
    __syncthreads();
    *(u16x8*)&Kl[kr0*72 + kc8] = ka;
    *(u16x8*)&Kl[(64+kr0)*72 + kc8] = kb;
    __syncthreads();
    if (kt < 15){
      ka = *(const u16x8*)&Kp[(size_t)((kt+1)*128 + kr0)*DH_ + kc8];
      kb = *(const u16x8*)&Kp[(size_t)((kt+1)*128 + 64 + kr0)*DH_ + kc8];
    }
    bf16x8 kf0 = *(const bf16x8*)&Kl[mrow*72 + g4];
    bf16x8 kf1 = *(const bf16x8*)&Kl[mrow*72 + 32 + g4];
    f32x4 s0 = {0.f,0.f,0.f,0.f}, s1 = {0.f,0.f,0.f,0.f};
    s0 = MFMA16(kf0, qf[0][0], s0); s0 = MFMA16(kf1, qf[0][1], s0);
    s1 = MFMA16(kf0, qf[1][0], s1); s1 = MFMA16(kf1, qf[1][1], s1);
    #pragma unroll
    for (int r=0;r<4;++r){
      racc0 += __expf(s0[r]*0.125f);
      racc1 += __expf(s1[r]*0.125f);
    }
  }
  racc0 += __shfl_xor(racc0, 16); racc0 += __shfl_xor(racc0, 32);
  racc1 += __shfl_xor(racc1, 16); racc1 += __shfl_xor(racc1, 32);
  if (lane < 16){ rsp[wid][lane] = racc0; rsp[wid][16+lane] = racc1; }
  __syncthreads();
  if (t < 32){
    float s = 0.f;
    #pragma unroll
    for (int w=0;w<8;++w) s += rsp[w][t];
    inv_rs[t] = 1.f/s;
  }
  __syncthreads();

  // ---------------- pass B: PV + coalesced attn stores ----------------
  const int qpv = wid>>2, d0 = (wid&3)*16;  // PV: wave owns 16q x 16d frag
  f32x4 o0 = {0.f,0.f,0.f,0.f}, o1 = {0.f,0.f,0.f,0.f};
  const int sr = t >> 4;                    // store: row in tile (0..31)
  const int sc = (t & 15) * 8;              // store: col (0..120)
  float* abase = attn + ((size_t)bh*L_ + q0 + sr)*L_ + sc;

  ka = *(const u16x8*)&Kp[(size_t)kr0*DH_ + kc8];
  kb = *(const u16x8*)&Kp[(size_t)(64+kr0)*DH_ + kc8];
  u16x8 va = *(const u16x8*)&Vp[(size_t)vr0*L_ + vcm];
  u16x8 vb = *(const u16x8*)&Vp[(size_t)(32+vr0)*L_ + vcm];
  for (int kt=0; kt<16; ++kt){
    __syncthreads();                         // Pt/Vl consumers of prev tile done
    *(u16x8*)&Kl[kr0*72 + kc8] = ka;
    *(u16x8*)&Kl[(64+kr0)*72 + kc8] = kb;
    *(u16x8*)&Vl[vr0*136 + vcm] = va;
    *(u16x8*)&Vl[(32+vr0)*136 + vcm] = vb;
    __syncthreads();
    if (kt < 15){
      ka = *(const u16x8*)&Kp[(size_t)((kt+1)*128 + kr0)*DH_ + kc8];
      kb = *(const u16x8*)&Kp[(size_t)((kt+1)*128 + 64 + kr0)*DH_ + kc8];
      va = *(const u16x8*)&Vp[(size_t)vr0*L_ + (kt+1)*128 + vcm];
      vb = *(const u16x8*)&Vp[(size_t)(32+vr0)*L_ + (kt+1)*128 + vcm];
    }
    bf16x8 kf0 = *(const bf16x8*)&Kl[mrow*72 + g4];
    bf16x8 kf1 = *(const bf16x8*)&Kl[mrow*72 + 32 + g4];
    f32x4 s0 = {0.f,0.f,0.f,0.f}, s1 = {0.f,0.f,0.f,0.f};
    s0 = MFMA16(kf0, qf[0][0], s0); s0 = MFMA16(kf1, qf[0][1], s0);
    s1 = MFMA16(kf0, qf[1][0], s1); s1 = MFMA16(kf1, qf[1][1], s1);
    u16x4 p0, p1;
    p0[0] = f2b(__expf(s0[0]*0.125f)); p0[1] = f2b(__expf(s0[1]*0.125f));
    p0[2] = f2b(__expf(s0[2]*0.125f)); p0[3] = f2b(__expf(s0[3]*0.125f));
    p1[0] = f2b(__expf(s1[0]*0.125f)); p1[1] = f2b(__expf(s1[1]*0.125f));
    p1[2] = f2b(__expf(s1[2]*0.125f)); p1[3] = f2b(__expf(s1[3]*0.125f));
    *(u16x4*)&Pt[(lane&15)*136 + wid*16 + (lane>>4)*4] = p0;
    *(u16x4*)&Pt[(16 + (lane&15))*136 + wid*16 + (lane>>4)*4] = p1;
    __syncthreads();                         // Pt/Vl ready
    // coalesced normalized attn store: 16 lanes cover 512 B contiguous
    {
      const u16x8 pv8 = *(const u16x8*)&Pt[sr*136 + sc];
      const float inv = inv_rs[sr];
      f32x4 w0, w1;
      w0[0]=b2f(pv8[0])*inv; w0[1]=b2f(pv8[1])*inv;
      w0[2]=b2f(pv8[2])*inv; w0[3]=b2f(pv8[3])*inv;
      w1[0]=b2f(pv8[4])*inv; w1[1]=b2f(pv8[5])*inv;
      w1[2]=b2f(pv8[6])*inv; w1[3]=b2f(pv8[7])*inv;
      __builtin_nontemporal_store(w0, (f32x4*)&abase[kt*128]);
      __builtin_nontemporal_store(w1, (f32x4*)&abase[kt*128 + 4]);
    }
    #pragma unroll
    for (int ms=0; ms<4; ++ms){
      bf16x8 pa = *(const bf16x8*)&Pt[(qpv*16 + (lane&15))*136 + ms*32 + g4];
      bf16x8 vv = *(const bf16x8*)&Vl[(d0 + (lane&15))*136 + ms*32 + g4];
      if (ms&1) o1 = MFMA16(pa, vv, o1); else o0 = MFMA16(pa, vv, o0);
    }
  }
  {
    const int b = bh>>3, h = bh&7;
    #pragma unroll
    for (int r=0;r<4;++r){
      const int qr = qpv*16 + (lane>>4)*4 + r;
      Og[((size_t)(b*L_ + q0 + qr))*D_ + h*DH_ + d0 + (lane&15)] = (o0[r]+o1[r])*inv_rs[qr];
    }
  }
}

// ---------------------------------------------------------------------------
// Kernel 3: residual add + LayerNorm over d=512 + slice to 508 cols.
// ---------------------------------------------------------------------------
__global__ __launch_bounds__(256) void ln_kernel(
    const float* __restrict__ Og, const float* __restrict__ inp,
    const float* __restrict__ gamma, const float* __restrict__ beta,
    float* __restrict__ out0)
{
  const int row = blockIdx.x, t = threadIdx.x;
  const int lane = t & 63, wid = t >> 6;
  const int c2 = t + 256;
  const float x1 = (t >= 2) ? inp[(size_t)row*DIN + t-2] : 0.f;
  const float x2 = (c2 < 510) ? inp[(size_t)row*DIN + c2-2] : 0.f;
  const float y1 = Og[(size_t)row*D_ + t]  + x1;
  const float y2 = Og[(size_t)row*D_ + c2] + x2;
  float s = y1 + y2, ss = y1*y1 + y2*y2;
  #pragma unroll
  for (int off=1; off<64; off<<=1){
    s  += __shfl_xor(s,  off);
    ss += __shfl_xor(ss, off);
  }
  __shared__ float red[4][2];
  if (lane == 0){ red[wid][0] = s; red[wid][1] = ss; }
  __syncthreads();
  s  = red[0][0]+red[1][0]+red[2][0]+red[3][0];
  ss = red[0][1]+red[1][1]+red[2][1]+red[3][1];
  const float mu   = s * (1.f/512.f);
  const float var  = ss * (1.f/512.f) - mu*mu;
  const float rstd = rsqrtf(var + 1e-6f);
  const float z1 = (y1 - mu)*rstd*gamma[t]  + beta[t];
  const float z2 = (y2 - mu)*rstd*gamma[c2] + beta[c2];
  if (t >= 2)   out0[(size_t)row*DIN + t-2]  = z1;
  if (c2 < 510) out0[(size_t)row*DIN + c2-2] = z2;
}

// ---------------------------------------------------------------------------
extern "C" void kernel_launch(void* const* d_in, const int* in_sizes, int n_in,
                              void* d_out, int out_size, void* d_ws, size_t ws_size,
                              hipStream_t stream) {
  const float* inp   = (const float*)d_in[0];
  const float* Wq    = (const float*)d_in[1];
  const float* Wk    = (const float*)d_in[2];
  const float* Wv    = (const float*)d_in[3];
  const float* gamma = (const float*)d_in[4];
  const float* beta  = (const float*)d_in[5];

  char* ws = (char*)d_ws;
  u16*   Qg = (u16*)(ws);                        // 4 MB
  u16*   Kg = (u16*)(ws + 4194304);              // 4 MB
  u16*   Vt = (u16*)(ws + 8388608);              // 4 MB, transposed [bh][dh][l]
  float* Og = (float*)(ws + 12582912);           // 8 MB (12M..20M)
  u16*   Xb = (u16*)(ws + 12582912);             // 4 MB   (aliases Og: dead
  u16*   Wb = (u16*)(ws + 16777216);             // 1.5 MB  before attn writes)

  float* out0 = (float*)d_out;                   // (2,2048,508)
  float* attn = out0 + 2080768;                  // (2,8,2048,2048)

  cvt_kernel <<<704, 512, 0, stream>>>(inp, Wq, Wk, Wv, Xb, Wb);
  proj_kernel<<<dim3(32,12), 512, 0, stream>>>(Xb, Wb, Qg, Kg, Vt);
  attn_kernel<<<dim3(64,16), 512, 0, stream>>>(Qg, Kg, Vt, attn, Og);
  ln_kernel  <<<4096, 256, 0, stream>>>(Og, inp, gamma, beta, out0);
}